// Round 14
// baseline (188.998 us; speedup 1.0000x reference)
//
#include <hip/hip_runtime.h>
#include <hip/hip_bf16.h>

#define D_MODEL 1024
#define N_HEAD  16
#define D_K     64
#define MAX_LEN 1000
#define B_      4
#define S_      1000
#define S_PAD   1024
#define M_PAD   (B_ * S_PAD)       // 4096
#define M_REAL  (B_ * S_)          // 4000
#define LN_EPS  1e-5f
#define SCALE_L2E 0.1803368801111204f   // 0.125 * log2(e)
#define REL_ROWS (2*MAX_LEN-1)     // 1999
#define NROWS   65536              // bh(64) * S_PAD rows of (row,head) partials

typedef __attribute__((ext_vector_type(8))) short short8;
typedef __attribute__((ext_vector_type(4))) float f32x4;

__device__ __forceinline__ unsigned short f2b(float f) {
    unsigned u = __builtin_bit_cast(unsigned, f);
    u = (u + 0x7FFFu + ((u >> 16) & 1u)) >> 16;
    return (unsigned short)u;
}

__device__ __forceinline__ unsigned short f2b_trunc(float f) {
    return (unsigned short)(__builtin_bit_cast(unsigned, f) >> 16);
}

__device__ __forceinline__ float b2f(unsigned short u) {
    return __builtin_bit_cast(float, (unsigned)u << 16);
}

__device__ __forceinline__ f32x4 mfma16(short8 a, short8 b, f32x4 c) {
    return __builtin_amdgcn_mfma_f32_16x16x32_bf16(a, b, c, 0, 0, 0);
}

__device__ __forceinline__ void gload_lds16(const void* g, void* l) {
    __builtin_amdgcn_global_load_lds(
        (const __attribute__((address_space(1))) unsigned int*)g,
        (__attribute__((address_space(3))) unsigned int*)l, 16, 0, 0);
}

// ---------------- merged fp32 -> bf16 convert (5 tensors) ----------------
__global__ void cvt_all(const float* __restrict__ s0, const float* __restrict__ s1,
                        const float* __restrict__ s2, const float* __restrict__ s3,
                        const float* __restrict__ s4,
                        unsigned short* __restrict__ d0, unsigned short* __restrict__ d1,
                        unsigned short* __restrict__ d2, unsigned short* __restrict__ d3,
                        unsigned short* __restrict__ d4) {
    int y = blockIdx.y;
    const float* in; unsigned short* out; int n4;
    switch (y) {
        case 0: in = s0; out = d0; n4 = 262144; break;
        case 1: in = s1; out = d1; n4 = 262144; break;
        case 2: in = s2; out = d2; n4 = 262144; break;
        case 3: in = s3; out = d3; n4 = 262144; break;
        default: in = s4; out = d4; n4 = REL_ROWS * D_K / 4; break;
    }
    int i = blockIdx.x * blockDim.x + threadIdx.x;
    if (i >= n4) return;
    float4 v = ((const float4*)in)[i];
    ushort4 o;
    o.x = f2b(v.x); o.y = f2b(v.y); o.z = f2b(v.z); o.w = f2b(v.w);
    ((ushort4*)out)[i] = o;
}

// ---------------- merged LayerNorm x3 -> bf16, padded rows zeroed ----------------
__global__ void ln_all(const float* __restrict__ xq, const float* __restrict__ xk,
                       const float* __restrict__ xv, const float* __restrict__ g,
                       const float* __restrict__ beta,
                       unsigned short* __restrict__ yq, unsigned short* __restrict__ yk,
                       unsigned short* __restrict__ yv) {
    int which = blockIdx.y;
    const float* x = which == 0 ? xq : which == 1 ? xk : xv;
    unsigned short* y = which == 0 ? yq : which == 1 ? yk : yv;

    int r = blockIdx.x;            // padded row index
    int b = r >> 10, i = r & 1023;
    unsigned short* yr = y + (size_t)r * D_MODEL;
    int tid = threadIdx.x;
    if (i >= S_) {
#pragma unroll
        for (int l = 0; l < 4; ++l) yr[tid + l * 256] = 0;
        return;
    }
    const float* xr = x + ((size_t)b * S_ + i) * D_MODEL;
    float v[4];
    float s = 0.f, sq = 0.f;
#pragma unroll
    for (int l = 0; l < 4; ++l) {
        v[l] = xr[tid + l * 256];
        s += v[l];
        sq += v[l] * v[l];
    }
#pragma unroll
    for (int o = 32; o > 0; o >>= 1) {
        s += __shfl_down(s, o, 64);
        sq += __shfl_down(sq, o, 64);
    }
    __shared__ float rs[4], rq[4];
    if ((tid & 63) == 0) { rs[tid >> 6] = s; rq[tid >> 6] = sq; }
    __syncthreads();
    if (tid == 0) {
        rs[0] = rs[0] + rs[1] + rs[2] + rs[3];
        rq[0] = rq[0] + rq[1] + rq[2] + rq[3];
    }
    __syncthreads();
    float mu = rs[0] * (1.0f / D_MODEL);
    float var = rq[0] * (1.0f / D_MODEL) - mu * mu;
    float rstd = rsqrtf(var + LN_EPS);
#pragma unroll
    for (int l = 0; l < 4; ++l) {
        int c = tid + l * 256;
        yr[c] = f2b((v[l] - mu) * rstd * g[c] + beta[c]);
    }
}

// ---------------- GEMM core: double-buffered K-loop (unchanged from r13) ----------------
template<int MODE>
__device__ __forceinline__ void gemm_body(
        const unsigned short* __restrict__ X, const unsigned short* __restrict__ W,
        const float* __restrict__ bias, const float* __restrict__ resid,
        unsigned short* __restrict__ Yb, float* __restrict__ Yf,
        unsigned short* As, unsigned short* Bs, int row0, int col0) {
    int tid = threadIdx.x;
    int lane = tid & 63, w = tid >> 6;
    int wr = w >> 1, wc = w & 1;
    int fr = lane & 15, fk = (lane >> 4) * 8;

    f32x4 acc[4][4];
#pragma unroll
    for (int fm = 0; fm < 4; ++fm)
#pragma unroll
        for (int fn = 0; fn < 4; ++fn) acc[fm][fn] = (f32x4)0.f;

    int c0 = (w * 2 + 0) * 64 + lane;
    int c1 = (w * 2 + 1) * 64 + lane;
    const unsigned short* xs0 = X + (size_t)(row0 + (c0 >> 2)) * 1024 + (c0 & 3) * 8;
    const unsigned short* xs1 = X + (size_t)(row0 + (c1 >> 2)) * 1024 + (c1 & 3) * 8;
    const unsigned short* ws0 = W + (size_t)(col0 + (c0 >> 2)) * 1024 + (c0 & 3) * 8;
    const unsigned short* ws1 = W + (size_t)(col0 + (c1 >> 2)) * 1024 + (c1 & 3) * 8;
    int do0 = (w * 2 + 0) * 512;
    int do1 = (w * 2 + 1) * 512;

    auto stage = [&](int buf, int k0) {
        gload_lds16(xs0 + k0, As + buf * 4096 + do0);
        gload_lds16(xs1 + k0, As + buf * 4096 + do1);
        gload_lds16(ws0 + k0, Bs + buf * 4096 + do0);
        gload_lds16(ws1 + k0, Bs + buf * 4096 + do1);
    };

    stage(0, 0);

    for (int it = 0; it < 32; ++it) {
        __syncthreads();
        if (it < 31) stage((it & 1) ^ 1, (it + 1) * 32);

        const unsigned short* Ab = As + (it & 1) * 4096;
        const unsigned short* Bb = Bs + (it & 1) * 4096;
        short8 a[4], b[4];
#pragma unroll
        for (int fm = 0; fm < 4; ++fm)
            a[fm] = *(const short8*)(Ab + (wr * 64 + fm * 16 + fr) * 32 + fk);
#pragma unroll
        for (int fn = 0; fn < 4; ++fn)
            b[fn] = *(const short8*)(Bb + (wc * 64 + fn * 16 + fr) * 32 + fk);
#pragma unroll
        for (int fm = 0; fm < 4; ++fm)
#pragma unroll
            for (int fn = 0; fn < 4; ++fn)
                acc[fm][fn] = mfma16(a[fm], b[fn], acc[fm][fn]);
    }

#pragma unroll
    for (int fm = 0; fm < 4; ++fm) {
#pragma unroll
        for (int fn = 0; fn < 4; ++fn) {
            int cg = col0 + wc * 64 + fn * 16 + fr;
            float bv = bias[cg];
#pragma unroll
            for (int r = 0; r < 4; ++r) {
                int rg = row0 + wr * 64 + fm * 16 + (lane >> 4) * 4 + r;
                float val = acc[fm][fn][r] + bv;
                int b_ = rg >> 10, i = rg & 1023;
                if (MODE == 0) {
                    int h = cg >> 6, d = cg & 63;
                    Yb[(((size_t)(b_ * N_HEAD + h)) * S_PAD + i) * D_K + d] = f2b(val);
                } else if (MODE == 1) {
                    int h = cg >> 6, d = cg & 63;
                    Yb[(((size_t)(b_ * N_HEAD + h)) * D_K + d) * S_PAD + i] = f2b(val);
                } else {
                    if (i < S_) {
                        size_t orow = (size_t)b_ * S_ + i;
                        Yf[orow * 1024 + cg] = val + resid[orow * 1024 + cg];
                    }
                }
            }
        }
    }
}

// merged Q/K/V projections: grid (8, 32, 3), XCD-chunked swizzle (768 = 8*96)
__global__ __launch_bounds__(256) void gemm_qkv(
        const unsigned short* __restrict__ qn, const unsigned short* __restrict__ kn,
        const unsigned short* __restrict__ vn,
        const unsigned short* __restrict__ wqb, const unsigned short* __restrict__ wkb,
        const unsigned short* __restrict__ wvb,
        const float* __restrict__ bq, const float* __restrict__ bk,
        const float* __restrict__ bv,
        unsigned short* __restrict__ qh, unsigned short* __restrict__ kh,
        unsigned short* __restrict__ vt) {
    __shared__ __align__(16) unsigned short As[2][128 * 32];
    __shared__ __align__(16) unsigned short Bs[2][128 * 32];
    int fid = blockIdx.x + (blockIdx.y << 3) + (blockIdx.z << 8);   // [0,768)
    int swz = (fid & 7) * 96 + (fid >> 3);                          // bijective
    int bz = swz >> 8;
    int rem = swz & 255;
    int row0 = (rem >> 3) * 128, col0 = (rem & 7) * 128;
    if (bz == 0)
        gemm_body<0>(qn, wqb, bq, nullptr, qh, nullptr, As[0], Bs[0], row0, col0);
    else if (bz == 1)
        gemm_body<0>(kn, wkb, bk, nullptr, kh, nullptr, As[0], Bs[0], row0, col0);
    else
        gemm_body<1>(vn, wvb, bv, nullptr, vt, nullptr, As[0], Bs[0], row0, col0);
}

// final output projection + residual: grid (8,32), XCD-chunked swizzle (256 = 8*32)
__global__ __launch_bounds__(256) void gemm_out(
        const unsigned short* __restrict__ X, const unsigned short* __restrict__ W,
        const float* __restrict__ bias, const float* __restrict__ resid,
        float* __restrict__ Yf) {
    __shared__ __align__(16) unsigned short As[2][128 * 32];
    __shared__ __align__(16) unsigned short Bs[2][128 * 32];
    int fid = blockIdx.x + (blockIdx.y << 3);       // [0,256)
    int swz = (fid & 7) * 32 + (fid >> 3);          // bijective
    int row0 = (swz >> 3) * 128, col0 = (swz & 7) * 128;
    gemm_body<2>(X, W, bias, resid, nullptr, Yf, As[0], Bs[0], row0, col0);
}

// ---------------- Flash attention, j-SPLIT: 1024 blocks, 8 iters each ----------------
// Block = (jhalf, bh, slab-octet); writes UNNORMALIZED partial O (bf16) + (m,l) per row.
#define QRW 84    // QR scratch stride (79 used)
#define PW  72    // P scratch stride (64 used), same buffer as QR
__device__ __forceinline__ void attn_slab(
        const unsigned short* __restrict__ Kc, const unsigned short* __restrict__ Vc,
        unsigned short* __restrict__ qp, const short8 (*rl)[2],
        short8 aq0, short8 aq1, f32x4* accO, float* mrun, float* lrun,
        bool mask_needed, int j0, int fr, int fk8, int rgrp, int rsw) {
    // ---- QK^T from LDS ----
    f32x4 accS[4];
#pragma unroll
    for (int fj = 0; fj < 4; ++fj) accS[fj] = (f32x4)0.f;
    __builtin_amdgcn_s_setprio(1);
#pragma unroll
    for (int fj = 0; fj < 4; ++fj) {
        int kb = (fj * 16 + fr) * 64 + fk8;
        accS[fj] = mfma16(aq0, *(const short8*)(Kc + (kb ^ rsw)), accS[fj]);
        accS[fj] = mfma16(aq1, *(const short8*)(Kc + ((kb + 32) ^ rsw)), accS[fj]);
    }
    // ---- Q @ relband^T; spill (truncated bf16) for diagonal gather ----
#pragma unroll
    for (int fu = 0; fu < 5; ++fu) {
        f32x4 qr = (f32x4)0.f;
        qr = mfma16(aq0, rl[fu][0], qr);
        qr = mfma16(aq1, rl[fu][1], qr);
#pragma unroll
        for (int r = 0; r < 4; ++r)
            qp[(rgrp + r) * QRW + fu * 16 + fr] = f2b_trunc(qr[r]);
    }
    __builtin_amdgcn_s_setprio(0);

    // ---- assemble scores (mask hoisted out of hot path) ----
    float sc[4][4];
#pragma unroll
    for (int fj = 0; fj < 4; ++fj) {
        int j_loc = fj * 16 + fr;
#pragma unroll
        for (int r = 0; r < 4; ++r) {
            int col = rgrp + r - j_loc + 63;   // in [0,78]
            sc[fj][r] = (accS[fj][r] + b2f(qp[(rgrp + r) * QRW + col])) * SCALE_L2E;
        }
    }
    if (mask_needed) {
#pragma unroll
        for (int fj = 0; fj < 4; ++fj) {
            int j_loc = fj * 16 + fr;
            if (j0 + j_loc >= S_) {
#pragma unroll
                for (int r = 0; r < 4; ++r) sc[fj][r] = -3e38f;
            }
        }
    }

    // ---- row max ----
    float pm[4];
#pragma unroll
    for (int r = 0; r < 4; ++r)
        pm[r] = fmaxf(fmaxf(sc[0][r], sc[1][r]), fmaxf(sc[2][r], sc[3][r]));
#pragma unroll
    for (int mask = 1; mask <= 8; mask <<= 1)
#pragma unroll
        for (int r = 0; r < 4; ++r)
            pm[r] = fmaxf(pm[r], __shfl_xor(pm[r], mask, 64));

    // ---- defer-max: rescale only when max grew by > 8 (log2 units) ----
    float dmax = fmaxf(fmaxf(pm[0] - mrun[0], pm[1] - mrun[1]),
                       fmaxf(pm[2] - mrun[2], pm[3] - mrun[3]));
    if (!__all(dmax <= 8.0f)) {
#pragma unroll
        for (int r = 0; r < 4; ++r) {
            float mn = fmaxf(mrun[r], pm[r]);
            float scl = __builtin_amdgcn_exp2f(mrun[r] - mn);
            mrun[r] = mn;
            lrun[r] *= scl;
#pragma unroll
            for (int fd = 0; fd < 4; ++fd) accO[fd][r] *= scl;
        }
    }

    // ---- exp (base-2) + truncated bf16 P store ----
    float rsum[4];
#pragma unroll
    for (int r = 0; r < 4; ++r) rsum[r] = 0.f;
#pragma unroll
    for (int fj = 0; fj < 4; ++fj) {
#pragma unroll
        for (int r = 0; r < 4; ++r) {
            float p = __builtin_amdgcn_exp2f(sc[fj][r] - mrun[r]);
            rsum[r] += p;
            qp[(rgrp + r) * PW + fj * 16 + fr] = f2b_trunc(p);
        }
    }
#pragma unroll
    for (int mask = 1; mask <= 8; mask <<= 1)
#pragma unroll
        for (int r = 0; r < 4; ++r)
            rsum[r] += __shfl_xor(rsum[r], mask, 64);
#pragma unroll
    for (int r = 0; r < 4; ++r) lrun[r] += rsum[r];

    // ---- PV from LDS ----
    short8 ap0 = *(const short8*)(qp + fr * PW + fk8);
    short8 ap1 = *(const short8*)(qp + fr * PW + 32 + fk8);
    __builtin_amdgcn_s_setprio(1);
#pragma unroll
    for (int fd = 0; fd < 4; ++fd) {
        int vb = (fd * 16 + fr) * 64 + fk8;
        accO[fd] = mfma16(ap0, *(const short8*)(Vc + (vb ^ rsw)), accO[fd]);
        accO[fd] = mfma16(ap1, *(const short8*)(Vc + ((vb + 32) ^ rsw)), accO[fd]);
    }
    __builtin_amdgcn_s_setprio(0);
}

__global__ __launch_bounds__(256, 2) void attn_mfma(
        const unsigned short* __restrict__ qh, const unsigned short* __restrict__ kh,
        const unsigned short* __restrict__ vt, const unsigned short* __restrict__ relb,
        unsigned short* __restrict__ pO0, unsigned short* __restrict__ pO1,
        float2* __restrict__ pml) {
    __shared__ __align__(16) unsigned short Ks[2][64 * 64];   // 16 KB
    __shared__ __align__(16) unsigned short Vs[2][64 * 64];   // 16 KB
    __shared__ __align__(16) unsigned short QP[4][16 * QRW];  // 10.5 KB

    int tid = threadIdx.x, lane = tid & 63, w = tid >> 6;
    int bid = blockIdx.x;                      // 1024 blocks
    int swz = (bid & 7) * 128 + (bid >> 3);    // XCD-chunked, bijective (1024 = 8*128)
    int jhalf = swz & 1;                       // j-half of this block
    int g = swz >> 1;                          // [0,512): (bh, slab octet)
    int bh = g >> 3;
    int i0a = (((g & 7) * 8) + 2 * w) * 16;    // slab a; slab b = i0a + 16
    int fr = lane & 15, fk8 = (lane >> 4) * 8, rgrp = (lane >> 4) * 4;
    int rsw = (fr & 7) << 3;                   // read-side XOR (ushort units)

    const unsigned short* kbase = kh + (size_t)bh * S_PAD * D_K;   // [i][d]
    const unsigned short* vtbase = vt + (size_t)bh * D_K * S_PAD;  // [d][i]

    const unsigned short* qpa = qh + ((size_t)bh * S_PAD + i0a + fr) * D_K + fk8;
    short8 aqa0 = *(const short8*)(qpa);
    short8 aqa1 = *(const short8*)(qpa + 32);
    const unsigned short* qpb = qpa + 16 * D_K;
    short8 aqb0 = *(const short8*)(qpb);
    short8 aqb1 = *(const short8*)(qpb + 32);

    f32x4 accOa[4], accOb[4];
    float mruna[4], lruna[4], mrunb[4], lrunb[4];
#pragma unroll
    for (int fd = 0; fd < 4; ++fd) { accOa[fd] = (f32x4)0.f; accOb[fd] = (f32x4)0.f; }
#pragma unroll
    for (int r = 0; r < 4; ++r) {
        mruna[r] = -3e38f; lruna[r] = 0.f;
        mrunb[r] = -3e38f; lrunb[r] = 0.f;
    }

    unsigned short* qp = QP[w];
    int row_in = lane >> 3, slot = lane & 7;
    int jbase = jhalf << 9;                    // 0 or 512

    auto stage = [&](int buf, int it2) {
        int j0s = jbase + it2 * 64;
#pragma unroll
        for (int cc = 0; cc < 2; ++cc) {
            int c = w * 2 + cc;
            int r = c * 8 + row_in;
            gload_lds16(kbase + (size_t)(j0s + r) * 64 + (slot ^ row_in) * 8,
                        &Ks[buf][c * 512]);
        }
#pragma unroll
        for (int cc = 0; cc < 2; ++cc) {
            int c = w * 2 + cc;
            int d = c * 8 + row_in;
            gload_lds16(vtbase + (size_t)d * S_PAD + j0s + (slot ^ row_in) * 8,
                        &Vs[buf][c * 512]);
        }
    };

    stage(0, 0);
    __syncthreads();   // tile 0 landed

    for (int it = 0; it < 8; ++it) {
        int cur = it & 1, j0 = jbase + it * 64;
        bool mask_needed = (j0 + 63 >= S_);

        // ---- ALL rel fragments for BOTH slabs issued BEFORE stage ----
        short8 rl[6][2];
        int ub = i0a - j0 + (S_ - D_K);
#pragma unroll
        for (int fu = 0; fu < 6; ++fu) {
            int u = ub + fu * 16 + fr;
            u = u < 0 ? 0 : (u > REL_ROWS - 1 ? REL_ROWS - 1 : u);
            const unsigned short* rp = relb + (size_t)u * D_K + fk8;
            rl[fu][0] = *(const short8*)(rp);
            rl[fu][1] = *(const short8*)(rp + 32);
        }
        __builtin_amdgcn_sched_barrier(0);   // pin rel loads ahead of stage issue

        if (it < 7) stage(cur ^ 1, it + 1);  // prefetch next tile (other buffer)

        attn_slab(Ks[cur], Vs[cur], qp, rl, aqa0, aqa1, accOa, mruna, lruna,
                  mask_needed, j0, fr, fk8, rgrp, rsw);
        attn_slab(Ks[cur], Vs[cur], qp, rl + 1, aqb0, aqb1, accOb, mrunb, lrunb,
                  mask_needed, j0, fr, fk8, rgrp, rsw);

        __syncthreads();   // next tile landed; all waves done with Ks/Vs[cur]
    }

    // ---- write UNNORMALIZED partials: O (bf16) + (m,l) per row ----
    unsigned short* pO = jhalf ? pO1 : pO0;
    float2* pmlh = pml + (jhalf << 16);
#pragma unroll
    for (int r = 0; r < 4; ++r) {
        int Ra = (bh << 10) + i0a + rgrp + r;
        int Rb = Ra + 16;
#pragma unroll
        for (int fd = 0; fd < 4; ++fd) {
            pO[((size_t)Ra << 6) + fd * 16 + fr] = f2b(accOa[fd][r]);
            pO[((size_t)Rb << 6) + fd * 16 + fr] = f2b(accOb[fd][r]);
        }
        if (fr == 0) {
            pmlh[Ra] = float2{mruna[r], lruna[r]};
            pmlh[Rb] = float2{mrunb[r], lrunb[r]};
        }
    }
}

// ---------------- combine: merge two j-half partials -> aout (bf16) ----------------
__global__ __launch_bounds__(256) void attn_combine(
        const unsigned short* __restrict__ pO0, const unsigned short* __restrict__ pO1,
        const float2* __restrict__ pml, unsigned short* __restrict__ aout) {
    int tid = threadIdx.x;
    int R = blockIdx.x * 16 + (tid >> 4);
    int dg = (tid & 15) * 4;
    float2 ml0 = pml[R];
    float2 ml1 = pml[NROWS + R];
    float m = fmaxf(ml0.x, ml1.x);
    float w0 = __builtin_amdgcn_exp2f(ml0.x - m);
    float w1 = __builtin_amdgcn_exp2f(ml1.x - m);
    float invl = 1.0f / (ml0.y * w0 + ml1.y * w1);
    ushort4 a4 = *(const ushort4*)(pO0 + ((size_t)R << 6) + dg);
    ushort4 b4 = *(const ushort4*)(pO1 + ((size_t)R << 6) + dg);
    int bh = R >> 10, i = R & 1023;
    int b_ = bh >> 4, h = bh & 15;
    ushort4 o;
    o.x = f2b((b2f(a4.x) * w0 + b2f(b4.x) * w1) * invl);
    o.y = f2b((b2f(a4.y) * w0 + b2f(b4.y) * w1) * invl);
    o.z = f2b((b2f(a4.z) * w0 + b2f(b4.z) * w1) * invl);
    o.w = f2b((b2f(a4.w) * w0 + b2f(b4.w) * w1) * invl);
    *(ushort4*)(aout + ((size_t)((b_ << 10) + i)) * 1024 + h * 64 + dg) = o;
}

extern "C" void kernel_launch(void* const* d_in, const int* in_sizes, int n_in,
                              void* d_out, int out_size, void* d_ws, size_t ws_size,
                              hipStream_t stream) {
    const float* q    = (const float*)d_in[0];
    const float* k    = (const float*)d_in[1];
    const float* v    = (const float*)d_in[2];
    const float* ln_g = (const float*)d_in[3];
    const float* ln_b = (const float*)d_in[4];
    const float* wq   = (const float*)d_in[5];
    const float* bq   = (const float*)d_in[6];
    const float* wk   = (const float*)d_in[7];
    const float* bk   = (const float*)d_in[8];
    const float* wv   = (const float*)d_in[9];
    const float* bv   = (const float*)d_in[10];
    const float* wo   = (const float*)d_in[11];
    const float* bo   = (const float*)d_in[12];
    const float* rel  = (const float*)d_in[13];
    float* out = (float*)d_out;

    const size_t TSZ = (size_t)M_PAD * D_MODEL;     // 4,194,304 ushorts
    unsigned short* ws   = (unsigned short*)d_ws;
    unsigned short* qn   = ws;
    unsigned short* kn   = qn + TSZ;
    unsigned short* vn   = kn + TSZ;
    unsigned short* qh   = vn + TSZ;
    unsigned short* kh   = qh + TSZ;
    unsigned short* vt   = kh + TSZ;
    unsigned short* aout = vt + TSZ;
    unsigned short* wqb  = aout + TSZ;
    unsigned short* wkb  = wqb + 1024 * 1024;
    unsigned short* wvb  = wkb + 1024 * 1024;
    unsigned short* wob  = wvb + 1024 * 1024;
    unsigned short* relb = wob + 1024 * 1024;

    // partials reuse buffers dead after gemm_qkv:
    unsigned short* pO0 = qn;                 // NROWS*64 ushorts = 4.2M  (== TSZ)
    unsigned short* pO1 = kn;
    float2* pml = (float2*)vn;                // 2*NROWS float2 = 1 MB

    cvt_all<<<dim3(1024, 5), 256, 0, stream>>>(wq, wk, wv, wo, rel,
                                               wqb, wkb, wvb, wob, relb);

    ln_all<<<dim3(M_PAD, 3), 256, 0, stream>>>(q, k, v, ln_g, ln_b, qn, kn, vn);

    gemm_qkv<<<dim3(8, 32, 3), 256, 0, stream>>>(qn, kn, vn, wqb, wkb, wvb,
                                                 bq, bk, bv, qh, kh, vt);

    attn_mfma<<<1024, 256, 0, stream>>>(qh, kh, vt, relb, pO0, pO1, pml);

    attn_combine<<<4096, 256, 0, stream>>>(pO0, pO1, pml, aout);

    gemm_out<<<dim3(8, 32), 256, 0, stream>>>(aout, wob, bo, q, out);
}

// Round 15
// 165.502 us; speedup vs baseline: 1.1420x; 1.1420x over previous
//
#include <hip/hip_runtime.h>
#include <hip/hip_bf16.h>

#define D_MODEL 1024
#define N_HEAD  16
#define D_K     64
#define MAX_LEN 1000
#define B_      4
#define S_      1000
#define S_PAD   1024
#define M_PAD   (B_ * S_PAD)       // 4096
#define M_REAL  (B_ * S_)          // 4000
#define LN_EPS  1e-5f
#define SCALE_L2E 0.1803368801111204f   // 0.125 * log2(e)
#define REL_ROWS (2*MAX_LEN-1)     // 1999

typedef __attribute__((ext_vector_type(8))) short short8;
typedef __attribute__((ext_vector_type(4))) float f32x4;

__device__ __forceinline__ unsigned short f2b(float f) {
    unsigned u = __builtin_bit_cast(unsigned, f);
    u = (u + 0x7FFFu + ((u >> 16) & 1u)) >> 16;
    return (unsigned short)u;
}

__device__ __forceinline__ unsigned short f2b_trunc(float f) {
    return (unsigned short)(__builtin_bit_cast(unsigned, f) >> 16);
}

__device__ __forceinline__ float b2f(unsigned short u) {
    return __builtin_bit_cast(float, (unsigned)u << 16);
}

__device__ __forceinline__ f32x4 mfma16(short8 a, short8 b, f32x4 c) {
    return __builtin_amdgcn_mfma_f32_16x16x32_bf16(a, b, c, 0, 0, 0);
}

__device__ __forceinline__ void gload_lds16(const void* g, void* l) {
    __builtin_amdgcn_global_load_lds(
        (const __attribute__((address_space(1))) unsigned int*)g,
        (__attribute__((address_space(3))) unsigned int*)l, 16, 0, 0);
}

// DPP row_ror rotation within 16-lane rows (VALU, not LDS pipe)
#define DPPROR(x, S) __builtin_bit_cast(float, __builtin_amdgcn_update_dpp( \
        0, __builtin_bit_cast(int, (x)), 0x120 | (S), 0xF, 0xF, false))

// ---------------- merged cvt (5 weight tensors) + LayerNorm x3, ONE launch ----------------
__global__ void prep_all(const float* __restrict__ wq, const float* __restrict__ wk,
                         const float* __restrict__ wv, const float* __restrict__ wo,
                         const float* __restrict__ rel,
                         unsigned short* __restrict__ wqb, unsigned short* __restrict__ wkb,
                         unsigned short* __restrict__ wvb, unsigned short* __restrict__ wob,
                         unsigned short* __restrict__ relb,
                         const float* __restrict__ xq, const float* __restrict__ xk,
                         const float* __restrict__ xv, const float* __restrict__ g,
                         const float* __restrict__ beta,
                         unsigned short* __restrict__ yq, unsigned short* __restrict__ yk,
                         unsigned short* __restrict__ yv) {
    __shared__ float rs[4], rq[4];
    int bid = blockIdx.x;
    int tid = threadIdx.x;
    if (bid < 5120) {
        int y = bid >> 10;
        const float* in; unsigned short* out; int n4;
        switch (y) {
            case 0: in = wq; out = wqb; n4 = 262144; break;
            case 1: in = wk; out = wkb; n4 = 262144; break;
            case 2: in = wv; out = wvb; n4 = 262144; break;
            case 3: in = wo; out = wob; n4 = 262144; break;
            default: in = rel; out = relb; n4 = REL_ROWS * D_K / 4; break;
        }
        int i = (bid & 1023) * 256 + tid;
        if (i >= n4) return;
        float4 v = ((const float4*)in)[i];
        ushort4 o;
        o.x = f2b(v.x); o.y = f2b(v.y); o.z = f2b(v.z); o.w = f2b(v.w);
        ((ushort4*)out)[i] = o;
        return;
    }
    int r2 = bid - 5120;
    int which = r2 >> 12;          // 0..2
    int r = r2 & 4095;             // padded row index
    const float* x = which == 0 ? xq : which == 1 ? xk : xv;
    unsigned short* y = which == 0 ? yq : which == 1 ? yk : yv;
    int b = r >> 10, i = r & 1023;
    unsigned short* yr = y + (size_t)r * D_MODEL;
    if (i >= S_) {
#pragma unroll
        for (int l = 0; l < 4; ++l) yr[tid + l * 256] = 0;
        return;
    }
    const float* xr = x + ((size_t)b * S_ + i) * D_MODEL;
    float v[4];
    float s = 0.f, sq = 0.f;
#pragma unroll
    for (int l = 0; l < 4; ++l) {
        v[l] = xr[tid + l * 256];
        s += v[l];
        sq += v[l] * v[l];
    }
#pragma unroll
    for (int o = 32; o > 0; o >>= 1) {
        s += __shfl_down(s, o, 64);
        sq += __shfl_down(sq, o, 64);
    }
    if ((tid & 63) == 0) { rs[tid >> 6] = s; rq[tid >> 6] = sq; }
    __syncthreads();
    if (tid == 0) {
        rs[0] = rs[0] + rs[1] + rs[2] + rs[3];
        rq[0] = rq[0] + rq[1] + rq[2] + rq[3];
    }
    __syncthreads();
    float mu = rs[0] * (1.0f / D_MODEL);
    float var = rq[0] * (1.0f / D_MODEL) - mu * mu;
    float rstd = rsqrtf(var + LN_EPS);
#pragma unroll
    for (int l = 0; l < 4; ++l) {
        int c = tid + l * 256;
        yr[c] = f2b((v[l] - mu) * rstd * g[c] + beta[c]);
    }
}

// ---------------- GEMM core: double-buffered K-loop (unchanged from r13) ----------------
template<int MODE>
__device__ __forceinline__ void gemm_body(
        const unsigned short* __restrict__ X, const unsigned short* __restrict__ W,
        const float* __restrict__ bias, const float* __restrict__ resid,
        unsigned short* __restrict__ Yb, float* __restrict__ Yf,
        unsigned short* As, unsigned short* Bs, int row0, int col0) {
    int tid = threadIdx.x;
    int lane = tid & 63, w = tid >> 6;
    int wr = w >> 1, wc = w & 1;
    int fr = lane & 15, fk = (lane >> 4) * 8;

    f32x4 acc[4][4];
#pragma unroll
    for (int fm = 0; fm < 4; ++fm)
#pragma unroll
        for (int fn = 0; fn < 4; ++fn) acc[fm][fn] = (f32x4)0.f;

    int c0 = (w * 2 + 0) * 64 + lane;
    int c1 = (w * 2 + 1) * 64 + lane;
    const unsigned short* xs0 = X + (size_t)(row0 + (c0 >> 2)) * 1024 + (c0 & 3) * 8;
    const unsigned short* xs1 = X + (size_t)(row0 + (c1 >> 2)) * 1024 + (c1 & 3) * 8;
    const unsigned short* ws0 = W + (size_t)(col0 + (c0 >> 2)) * 1024 + (c0 & 3) * 8;
    const unsigned short* ws1 = W + (size_t)(col0 + (c1 >> 2)) * 1024 + (c1 & 3) * 8;
    int do0 = (w * 2 + 0) * 512;
    int do1 = (w * 2 + 1) * 512;

    auto stage = [&](int buf, int k0) {
        gload_lds16(xs0 + k0, As + buf * 4096 + do0);
        gload_lds16(xs1 + k0, As + buf * 4096 + do1);
        gload_lds16(ws0 + k0, Bs + buf * 4096 + do0);
        gload_lds16(ws1 + k0, Bs + buf * 4096 + do1);
    };

    stage(0, 0);

    for (int it = 0; it < 32; ++it) {
        __syncthreads();
        if (it < 31) stage((it & 1) ^ 1, (it + 1) * 32);

        const unsigned short* Ab = As + (it & 1) * 4096;
        const unsigned short* Bb = Bs + (it & 1) * 4096;
        short8 a[4], b[4];
#pragma unroll
        for (int fm = 0; fm < 4; ++fm)
            a[fm] = *(const short8*)(Ab + (wr * 64 + fm * 16 + fr) * 32 + fk);
#pragma unroll
        for (int fn = 0; fn < 4; ++fn)
            b[fn] = *(const short8*)(Bb + (wc * 64 + fn * 16 + fr) * 32 + fk);
#pragma unroll
        for (int fm = 0; fm < 4; ++fm)
#pragma unroll
            for (int fn = 0; fn < 4; ++fn)
                acc[fm][fn] = mfma16(a[fm], b[fn], acc[fm][fn]);
    }

#pragma unroll
    for (int fm = 0; fm < 4; ++fm) {
#pragma unroll
        for (int fn = 0; fn < 4; ++fn) {
            int cg = col0 + wc * 64 + fn * 16 + fr;
            float bv = bias[cg];
#pragma unroll
            for (int r = 0; r < 4; ++r) {
                int rg = row0 + wr * 64 + fm * 16 + (lane >> 4) * 4 + r;
                float val = acc[fm][fn][r] + bv;
                int b_ = rg >> 10, i = rg & 1023;
                if (MODE == 0) {
                    int h = cg >> 6, d = cg & 63;
                    Yb[(((size_t)(b_ * N_HEAD + h)) * S_PAD + i) * D_K + d] = f2b(val);
                } else if (MODE == 1) {
                    int h = cg >> 6, d = cg & 63;
                    Yb[(((size_t)(b_ * N_HEAD + h)) * D_K + d) * S_PAD + i] = f2b(val);
                } else {
                    if (i < S_) {
                        size_t orow = (size_t)b_ * S_ + i;
                        Yf[orow * 1024 + cg] = val + resid[orow * 1024 + cg];
                    }
                }
            }
        }
    }
}

// merged Q/K/V projections: grid (8, 32, 3), XCD-chunked swizzle (768 = 8*96)
__global__ __launch_bounds__(256) void gemm_qkv(
        const unsigned short* __restrict__ qn, const unsigned short* __restrict__ kn,
        const unsigned short* __restrict__ vn,
        const unsigned short* __restrict__ wqb, const unsigned short* __restrict__ wkb,
        const unsigned short* __restrict__ wvb,
        const float* __restrict__ bq, const float* __restrict__ bk,
        const float* __restrict__ bv,
        unsigned short* __restrict__ qh, unsigned short* __restrict__ kh,
        unsigned short* __restrict__ vt) {
    __shared__ __align__(16) unsigned short As[2][128 * 32];
    __shared__ __align__(16) unsigned short Bs[2][128 * 32];
    int fid = blockIdx.x + (blockIdx.y << 3) + (blockIdx.z << 8);   // [0,768)
    int swz = (fid & 7) * 96 + (fid >> 3);                          // bijective
    int bz = swz >> 8;
    int rem = swz & 255;
    int row0 = (rem >> 3) * 128, col0 = (rem & 7) * 128;
    if (bz == 0)
        gemm_body<0>(qn, wqb, bq, nullptr, qh, nullptr, As[0], Bs[0], row0, col0);
    else if (bz == 1)
        gemm_body<0>(kn, wkb, bk, nullptr, kh, nullptr, As[0], Bs[0], row0, col0);
    else
        gemm_body<1>(vn, wvb, bv, nullptr, vt, nullptr, As[0], Bs[0], row0, col0);
}

// final output projection + residual: grid (8,32), XCD-chunked swizzle (256 = 8*32)
__global__ __launch_bounds__(256) void gemm_out(
        const unsigned short* __restrict__ X, const unsigned short* __restrict__ W,
        const float* __restrict__ bias, const float* __restrict__ resid,
        float* __restrict__ Yf) {
    __shared__ __align__(16) unsigned short As[2][128 * 32];
    __shared__ __align__(16) unsigned short Bs[2][128 * 32];
    int fid = blockIdx.x + (blockIdx.y << 3);       // [0,256)
    int swz = (fid & 7) * 32 + (fid >> 3);          // bijective
    int row0 = (swz >> 3) * 128, col0 = (swz & 7) * 128;
    gemm_body<2>(X, W, bias, resid, nullptr, Yf, As[0], Bs[0], row0, col0);
}

// ---------------- Flash attention: r13 structure + b64 QR spill + DPP reductions ----------------
// QR scratch TRANSPOSED [u_col][i_row], stride 20 ushorts (40 B = 10 banks, b64-aligned).
#define QRT 20
#define QPW 1600  // per-wave QP region: 80 cols * 20
#define PW  72    // P scratch stride (64 used), same buffer (disjoint lifetime)
__device__ __forceinline__ void attn_slab(
        const unsigned short* __restrict__ Kc, const unsigned short* __restrict__ Vc,
        unsigned short* __restrict__ qp, const short8 (*rl)[2],
        short8 aq0, short8 aq1, f32x4* accO, float* mrun, float* lrun,
        bool mask_needed, int j0, int fr, int fk8, int rgrp, int rsw) {
    // ---- QK^T from LDS ----
    f32x4 accS[4];
#pragma unroll
    for (int fj = 0; fj < 4; ++fj) accS[fj] = (f32x4)0.f;
    __builtin_amdgcn_s_setprio(1);
#pragma unroll
    for (int fj = 0; fj < 4; ++fj) {
        int kb = (fj * 16 + fr) * 64 + fk8;
        accS[fj] = mfma16(aq0, *(const short8*)(Kc + (kb ^ rsw)), accS[fj]);
        accS[fj] = mfma16(aq1, *(const short8*)(Kc + ((kb + 32) ^ rsw)), accS[fj]);
    }
    // ---- Q @ relband^T; spill TRANSPOSED as one b64 per fragment ----
#pragma unroll
    for (int fu = 0; fu < 5; ++fu) {
        f32x4 qr = (f32x4)0.f;
        qr = mfma16(aq0, rl[fu][0], qr);
        qr = mfma16(aq1, rl[fu][1], qr);
        unsigned lo = ((unsigned)f2b_trunc(qr[1]) << 16) | f2b_trunc(qr[0]);
        unsigned hi = ((unsigned)f2b_trunc(qr[3]) << 16) | f2b_trunc(qr[2]);
        *(uint2*)(qp + (fu * 16 + fr) * QRT + rgrp) = uint2{lo, hi};
    }
    __builtin_amdgcn_s_setprio(0);

    // ---- assemble scores (gather from transposed QR) ----
    float sc[4][4];
#pragma unroll
    for (int fj = 0; fj < 4; ++fj) {
        int j_loc = fj * 16 + fr;
#pragma unroll
        for (int r = 0; r < 4; ++r) {
            int col = rgrp + r - j_loc + 63;   // in [0,78]
            sc[fj][r] = (accS[fj][r] + b2f(qp[col * QRT + rgrp + r])) * SCALE_L2E;
        }
    }
    if (mask_needed) {
#pragma unroll
        for (int fj = 0; fj < 4; ++fj) {
            int j_loc = fj * 16 + fr;
            if (j0 + j_loc >= S_) {
#pragma unroll
                for (int r = 0; r < 4; ++r) sc[fj][r] = -3e38f;
            }
        }
    }

    // ---- row max via DPP row_ror (VALU pipe, not LDS) ----
    float pm[4];
#pragma unroll
    for (int r = 0; r < 4; ++r) {
        float m0 = fmaxf(fmaxf(sc[0][r], sc[1][r]), fmaxf(sc[2][r], sc[3][r]));
        m0 = fmaxf(m0, DPPROR(m0, 1));
        m0 = fmaxf(m0, DPPROR(m0, 2));
        m0 = fmaxf(m0, DPPROR(m0, 4));
        m0 = fmaxf(m0, DPPROR(m0, 8));
        pm[r] = m0;
    }

    // ---- defer-max: rescale only when max grew by > 8 (log2 units) ----
    float dmax = fmaxf(fmaxf(pm[0] - mrun[0], pm[1] - mrun[1]),
                       fmaxf(pm[2] - mrun[2], pm[3] - mrun[3]));
    if (!__all(dmax <= 8.0f)) {
#pragma unroll
        for (int r = 0; r < 4; ++r) {
            float mn = fmaxf(mrun[r], pm[r]);
            float scl = __builtin_amdgcn_exp2f(mrun[r] - mn);
            mrun[r] = mn;
            lrun[r] *= scl;
#pragma unroll
            for (int fd = 0; fd < 4; ++fd) accO[fd][r] *= scl;
        }
    }

    // ---- exp (base-2) + truncated bf16 P store; row-sum via DPP ----
    float rsum[4];
#pragma unroll
    for (int r = 0; r < 4; ++r) rsum[r] = 0.f;
#pragma unroll
    for (int fj = 0; fj < 4; ++fj) {
#pragma unroll
        for (int r = 0; r < 4; ++r) {
            float p = __builtin_amdgcn_exp2f(sc[fj][r] - mrun[r]);
            rsum[r] += p;
            qp[(rgrp + r) * PW + fj * 16 + fr] = f2b_trunc(p);
        }
    }
#pragma unroll
    for (int r = 0; r < 4; ++r) {
        float s0 = rsum[r];
        s0 += DPPROR(s0, 1);
        s0 += DPPROR(s0, 2);
        s0 += DPPROR(s0, 4);
        s0 += DPPROR(s0, 8);
        lrun[r] += s0;
    }

    // ---- PV from LDS ----
    short8 ap0 = *(const short8*)(qp + fr * PW + fk8);
    short8 ap1 = *(const short8*)(qp + fr * PW + 32 + fk8);
    __builtin_amdgcn_s_setprio(1);
#pragma unroll
    for (int fd = 0; fd < 4; ++fd) {
        int vb = (fd * 16 + fr) * 64 + fk8;
        accO[fd] = mfma16(ap0, *(const short8*)(Vc + (vb ^ rsw)), accO[fd]);
        accO[fd] = mfma16(ap1, *(const short8*)(Vc + ((vb + 32) ^ rsw)), accO[fd]);
    }
    __builtin_amdgcn_s_setprio(0);
}

__global__ __launch_bounds__(256, 2) void attn_mfma(
        const unsigned short* __restrict__ qh, const unsigned short* __restrict__ kh,
        const unsigned short* __restrict__ vt, const unsigned short* __restrict__ relb,
        unsigned short* __restrict__ aout) {
    __shared__ __align__(16) unsigned short Ks[2][64 * 64];   // 16 KB
    __shared__ __align__(16) unsigned short Vs[2][64 * 64];   // 16 KB
    __shared__ __align__(16) unsigned short QP[4][QPW];       // 12.5 KB

    int tid = threadIdx.x, lane = tid & 63, w = tid >> 6;
    int bid = blockIdx.x;                      // 512 blocks
    int swz = (bid & 7) * 64 + (bid >> 3);     // XCD-chunked, bijective (512 = 8*64)
    int bh = swz >> 3;                         // uniform across block
    int i0a = (((swz & 7) * 8) + 2 * w) * 16;  // slab a; slab b = i0a + 16
    int fr = lane & 15, fk8 = (lane >> 4) * 8, rgrp = (lane >> 4) * 4;
    int rsw = (fr & 7) << 3;                   // read-side XOR (ushort units)

    const unsigned short* kbase = kh + (size_t)bh * S_PAD * D_K;   // [i][d]
    const unsigned short* vtbase = vt + (size_t)bh * D_K * S_PAD;  // [d][i]

    const unsigned short* qpa = qh + ((size_t)bh * S_PAD + i0a + fr) * D_K + fk8;
    short8 aqa0 = *(const short8*)(qpa);
    short8 aqa1 = *(const short8*)(qpa + 32);
    const unsigned short* qpb = qpa + 16 * D_K;
    short8 aqb0 = *(const short8*)(qpb);
    short8 aqb1 = *(const short8*)(qpb + 32);

    f32x4 accOa[4], accOb[4];
    float mruna[4], lruna[4], mrunb[4], lrunb[4];
#pragma unroll
    for (int fd = 0; fd < 4; ++fd) { accOa[fd] = (f32x4)0.f; accOb[fd] = (f32x4)0.f; }
#pragma unroll
    for (int r = 0; r < 4; ++r) {
        mruna[r] = -3e38f; lruna[r] = 0.f;
        mrunb[r] = -3e38f; lrunb[r] = 0.f;
    }

    unsigned short* qp = QP[w];
    int row_in = lane >> 3, slot = lane & 7;

    auto stage = [&](int buf, int it2) {
        int j0s = it2 * 64;
#pragma unroll
        for (int cc = 0; cc < 2; ++cc) {
            int c = w * 2 + cc;
            int r = c * 8 + row_in;
            gload_lds16(kbase + (size_t)(j0s + r) * 64 + (slot ^ row_in) * 8,
                        &Ks[buf][c * 512]);
        }
#pragma unroll
        for (int cc = 0; cc < 2; ++cc) {
            int c = w * 2 + cc;
            int d = c * 8 + row_in;
            gload_lds16(vtbase + (size_t)d * S_PAD + j0s + (slot ^ row_in) * 8,
                        &Vs[buf][c * 512]);
        }
    };

    stage(0, 0);
    __syncthreads();   // tile 0 landed

    for (int it = 0; it < 16; ++it) {
        int cur = it & 1, j0 = it * 64;
        bool mask_needed = (j0 + 63 >= S_);

        // ---- ALL rel fragments for BOTH slabs issued BEFORE stage ----
        short8 rl[6][2];
        int ub = i0a - j0 + (S_ - D_K);
#pragma unroll
        for (int fu = 0; fu < 6; ++fu) {
            int u = ub + fu * 16 + fr;
            u = u < 0 ? 0 : (u > REL_ROWS - 1 ? REL_ROWS - 1 : u);
            const unsigned short* rp = relb + (size_t)u * D_K + fk8;
            rl[fu][0] = *(const short8*)(rp);
            rl[fu][1] = *(const short8*)(rp + 32);
        }
        __builtin_amdgcn_sched_barrier(0);   // pin rel loads ahead of stage issue

        if (it < 15) stage(cur ^ 1, it + 1);  // prefetch next tile (other buffer)

        attn_slab(Ks[cur], Vs[cur], qp, rl, aqa0, aqa1, accOa, mruna, lruna,
                  mask_needed, j0, fr, fk8, rgrp, rsw);
        attn_slab(Ks[cur], Vs[cur], qp, rl + 1, aqb0, aqb1, accOb, mrunb, lrunb,
                  mask_needed, j0, fr, fk8, rgrp, rsw);

        __syncthreads();   // next tile landed; all waves done with Ks/Vs[cur]
    }

    // ---- normalize + store both slabs ----
    int b_ = bh >> 4, h = bh & 15;
#pragma unroll
    for (int r = 0; r < 4; ++r) {
        float inva = 1.0f / lruna[r];
        float invb = 1.0f / lrunb[r];
        int ma = b_ * S_PAD + i0a + rgrp + r;
        int mb = ma + 16;
#pragma unroll
        for (int fd = 0; fd < 4; ++fd) {
            int c = h * D_K + fd * 16 + fr;
            aout[(size_t)ma * D_MODEL + c] = f2b(accOa[fd][r] * inva);
            aout[(size_t)mb * D_MODEL + c] = f2b(accOb[fd][r] * invb);
        }
    }
}

extern "C" void kernel_launch(void* const* d_in, const int* in_sizes, int n_in,
                              void* d_out, int out_size, void* d_ws, size_t ws_size,
                              hipStream_t stream) {
    const float* q    = (const float*)d_in[0];
    const float* k    = (const float*)d_in[1];
    const float* v    = (const float*)d_in[2];
    const float* ln_g = (const float*)d_in[3];
    const float* ln_b = (const float*)d_in[4];
    const float* wq   = (const float*)d_in[5];
    const float* bq   = (const float*)d_in[6];
    const float* wk   = (const float*)d_in[7];
    const float* bk   = (const float*)d_in[8];
    const float* wv   = (const float*)d_in[9];
    const float* bv   = (const float*)d_in[10];
    const float* wo   = (const float*)d_in[11];
    const float* bo   = (const float*)d_in[12];
    const float* rel  = (const float*)d_in[13];
    float* out = (float*)d_out;

    const size_t TSZ = (size_t)M_PAD * D_MODEL;     // 4,194,304 ushorts
    unsigned short* ws   = (unsigned short*)d_ws;
    unsigned short* qn   = ws;
    unsigned short* kn   = qn + TSZ;
    unsigned short* vn   = kn + TSZ;
    unsigned short* qh   = vn + TSZ;
    unsigned short* kh   = qh + TSZ;
    unsigned short* vt   = kh + TSZ;
    unsigned short* aout = vt + TSZ;
    unsigned short* wqb  = aout + TSZ;
    unsigned short* wkb  = wqb + 1024 * 1024;
    unsigned short* wvb  = wkb + 1024 * 1024;
    unsigned short* wob  = wvb + 1024 * 1024;
    unsigned short* relb = wob + 1024 * 1024;

    // weights cvt + 3 LayerNorms in ONE launch
    prep_all<<<5120 + 3 * 4096, 256, 0, stream>>>(
        wq, wk, wv, wo, rel, wqb, wkb, wvb, wob, relb,
        q, k, v, ln_g, ln_b, qn, kn, vn);

    gemm_qkv<<<dim3(8, 32, 3), 256, 0, stream>>>(qn, kn, vn, wqb, wkb, wvb,
                                                 bq, bk, bv, qh, kh, vt);

    attn_mfma<<<512, 256, 0, stream>>>(qh, kh, vt, relb, aout);

    gemm_out<<<dim3(8, 32), 256, 0, stream>>>(aout, wob, bo, q, out);
}